// Round 1
// baseline (100.876 us; speedup 1.0000x reference)
//
#include <hip/hip_runtime.h>
#include <cfloat>

// Problem constants (fixed by reference): B=4, N=M=8192, D=3, fp32.
#define BB    4
#define NN    8192
#define MM    8192
#define NPTS  (BB * NN)         // 32768 queries per direction
#define QT    8                 // queries per thread (register tile)
#define BLK   256
#define QB    (BLK * QT)        // 2048 queries per block
#define QBLKS (NPTS / QB)       // 16 query-blocks per direction
#define SEG   32                // target segments per batch
#define TSEG  (MM / SEG)        // 256 targets per block (4 KB LDS)

// Monotone float->uint mapping so uint atomicMin == float min (handles negatives).
__device__ __forceinline__ unsigned int fmap(float f) {
    unsigned int u = __float_as_uint(f);
    return (u & 0x80000000u) ? ~u : (u | 0x80000000u);
}
__device__ __forceinline__ float funmap(unsigned int u) {
    u = (u & 0x80000000u) ? (u & 0x7FFFFFFFu) : ~u;
    return __uint_as_float(u);
}

// Trivial init: mins = +inf (ordered-uint max), out = 0. No input reads.
__global__ void chamfer_init(unsigned int* __restrict__ mins,
                             float* __restrict__ out, int out_size) {
    int i = blockIdx.x * blockDim.x + threadIdx.x;       // 16384 threads
    ((uint4*)mins)[i] = make_uint4(~0u, ~0u, ~0u, ~0u);  // 65536 uints = 256 KB
    if (i < out_size) out[i] = 0.f;
}

// Each thread: QT=8 query points vs TSEG=256 targets staged in LDS.
// Targets staged directly from raw float3 input; w = ||t||^2/2 computed at stage.
// Tracks min_j( ||t||^2/2 - q.t ); final value = 2*(min + ||q||^2/2) in reduce.
// Inner loop processes target PAIRS: 6 fma + 1 min3 = 3.5 VALU ops per pair.
__global__ void __launch_bounds__(256, 4) chamfer_main(
        const float* __restrict__ gts, const float* __restrict__ preds,
        unsigned int* __restrict__ mins) {
    __shared__ float4 st[TSEG];

    int bid  = blockIdx.x;          // grid = 2 * QBLKS * SEG = 1024
    int dir  = bid >> 9;            // 512 blocks per direction
    int rest = bid & 511;
    int qblk = rest >> 5;           // 16 query-blocks per direction
    int seg  = rest & 31;           // 32 target segments
    int b    = qblk >> 2;           // 4 query-blocks per batch (uniform per block)

    const float* __restrict__ Q = dir ? preds : gts;
    const float* __restrict__ T = dir ? gts : preds;
    const float* __restrict__ tp = T + (size_t)(b * MM + seg * TSEG) * 3;

    // Stage this segment's targets from raw float3, computing w on the fly.
    {
        int j = threadIdx.x;
        float x = tp[3*j + 0], y = tp[3*j + 1], z = tp[3*j + 2];
        st[j] = make_float4(x, y, z, 0.5f * (x*x + y*y + z*z));
    }

    int q0 = qblk * QB + threadIdx.x;            // query index within direction
    const float* __restrict__ qp = Q + (size_t)q0 * 3;
    float qx[QT], qy[QT], qz[QT], m[QT];
    #pragma unroll
    for (int k = 0; k < QT; ++k) {
        qx[k] = qp[3*(256*k) + 0];
        qy[k] = qp[3*(256*k) + 1];
        qz[k] = qp[3*(256*k) + 2];
        m[k]  = FLT_MAX;
    }
    __syncthreads();

    #pragma unroll 2
    for (int j = 0; j < TSEG; j += 2) {
        float4 t0 = st[j], t1 = st[j+1];         // broadcast ds_read_b128 x2
        #pragma unroll
        for (int k = 0; k < QT; ++k) {
            float s0 = fmaf(-qx[k], t0.x,
                       fmaf(-qy[k], t0.y,
                       fmaf(-qz[k], t0.z, t0.w)));
            float s1 = fmaf(-qx[k], t1.x,
                       fmaf(-qy[k], t1.y,
                       fmaf(-qz[k], t1.z, t1.w)));
            m[k] = fminf(fminf(m[k], s0), s1);   // fuses to v_min3_f32
        }
    }

    #pragma unroll
    for (int k = 0; k < QT; ++k)
        atomicMin(&mins[dir * NPTS + q0 + 256*k], fmap(m[k]));
}

// Sum over all points: 2*(unmap(min) + ||q||^2/2), w recomputed from raw input.
__global__ void chamfer_reduce(const unsigned int* __restrict__ mins,
                               const float* __restrict__ gts,
                               const float* __restrict__ preds,
                               float* __restrict__ out) {
    int g = blockIdx.x * blockDim.x + threadIdx.x;   // 0 .. 2*NPTS-1
    const float* p = (g < NPTS) ? gts + (size_t)g * 3
                                : preds + (size_t)(g - NPTS) * 3;
    float x = p[0], y = p[1], z = p[2];
    float val = 2.0f * (funmap(mins[g]) + 0.5f * (x*x + y*y + z*z));

    #pragma unroll
    for (int off = 32; off > 0; off >>= 1)
        val += __shfl_down(val, off, 64);

    __shared__ float s[4];
    int lane = threadIdx.x & 63;
    int w_id = threadIdx.x >> 6;
    if (lane == 0) s[w_id] = val;
    __syncthreads();
    if (threadIdx.x == 0)
        atomicAdd(out, s[0] + s[1] + s[2] + s[3]);
}

extern "C" void kernel_launch(void* const* d_in, const int* in_sizes, int n_in,
                              void* d_out, int out_size, void* d_ws, size_t ws_size,
                              hipStream_t stream) {
    const float* gts   = (const float*)d_in[0];
    const float* preds = (const float*)d_in[1];
    float* out = (float*)d_out;
    unsigned int* mins = (unsigned int*)d_ws;        // 256 KB

    chamfer_init  <<<64, 256, 0, stream>>>(mins, out, out_size);
    chamfer_main  <<<2 * QBLKS * SEG, 256, 0, stream>>>(gts, preds, mins);
    chamfer_reduce<<<(2 * NPTS) / 256, 256, 0, stream>>>(mins, gts, preds, out);
}